// Round 3
// baseline (713.467 us; speedup 1.0000x reference)
//
#include <hip/hip_runtime.h>

// TT embedding bag, load-balanced + software-pipelined.
// idx = pair*50 + d2, pair < 2500, d2 < 50.
// t_table[pair][kk*32+s] = sum_r core0[d0][x*32+r]*core1[d1][r*128+y*32+s], kk=x*4+y
// core2T[d2][z*32+r]     = core2[d2][r*8+z]
// emb[kk*8+z] = dot32(t_table[pair][kk*32..], core2T[d2][z*32..])

#define PAIRS 2500
#define TROW 512
#define CHT 64   // TT positions per block
#define CHC 64   // cached positions per block

__global__ __launch_bounds__(256) void build_tables_kernel(
    const float* __restrict__ core0, const float* __restrict__ core1,
    const float* __restrict__ core2, float* __restrict__ t_table,
    float* __restrict__ core2T) {
  const int bid = blockIdx.x;
  const int tid = threadIdx.x;
  if (bid < PAIRS) {
    __shared__ float c0[128];
    __shared__ float c1[4096];
    const int d0 = bid / 50, d1 = bid - d0 * 50;
    const float4* src1 = reinterpret_cast<const float4*>(core1 + (size_t)d1 * 4096);
    float4* dst1 = reinterpret_cast<float4*>(c1);
    for (int i = tid; i < 1024; i += 256) dst1[i] = src1[i];
    if (tid < 32) {
      reinterpret_cast<float4*>(c0)[tid] =
          reinterpret_cast<const float4*>(core0 + (size_t)d0 * 128)[tid];
    }
    __syncthreads();
#pragma unroll
    for (int q = 0; q < 2; ++q) {
      const int o = tid + q * 256;
      const int kk = o >> 5, s = o & 31;
      const int x = kk >> 2, y = kk & 3;
      float acc = 0.f;
#pragma unroll
      for (int r = 0; r < 32; ++r)
        acc += c0[x * 32 + r] * c1[r * 128 + y * 32 + s];
      t_table[(size_t)bid * TROW + o] = acc;
    }
  } else {
    const int d2 = bid - PAIRS;
    if (tid < 256) {
      const int z = tid >> 5, r = tid & 31;
      core2T[(size_t)d2 * 256 + tid] = core2[(size_t)d2 * 256 + r * 8 + z];
    }
  }
}

__device__ __forceinline__ int bag_search(const int* __restrict__ offs,
                                          int nbags, int p) {
  int lo = 0, hi = nbags;
  while (hi - lo > 1) {
    int m = (lo + hi) >> 1;
    if (offs[m] <= p) lo = m; else hi = m;
  }
  return lo;
}

__global__ void bag_main_kernel(
    const int* __restrict__ indices, const int* __restrict__ offsets,
    const int* __restrict__ cached_indices, const int* __restrict__ cached_offsets,
    const float* __restrict__ cache_table, const float* __restrict__ t_table,
    const float* __restrict__ core2T, float* __restrict__ out,
    int n, int nbags, int ntt_blocks) {
  const int tid = threadIdx.x;
  const int bid = blockIdx.x;

  if (bid < ntt_blocks) {
    // ---------------- TT part: 2-deep register ping-pong ----------------
    __shared__ int spair[CHT], sd2[CHT], sbag[CHT];
    const int base = bid * CHT;
    const int count = min(CHT, n - base);
    if (tid < count) {
      const int p = base + tid;
      const int idx = indices[p];
      const int pr = idx / 50;
      spair[tid] = pr;
      sd2[tid] = idx - pr * 50;
      sbag[tid] = bag_search(offsets, nbags, p);
    }
    __syncthreads();

    const int kk = tid >> 3, z = tid & 7;
    const float* tbase = t_table + (size_t)kk * 32;
    const float* cbase = core2T + (size_t)z * 32;

    float4 tA[8], cA[8], tB[8], cB[8];
    {
      const float4* tp = reinterpret_cast<const float4*>(tbase + (size_t)spair[0] * TROW);
      const float4* cp = reinterpret_cast<const float4*>(cbase + (size_t)sd2[0] * 256);
#pragma unroll
      for (int r = 0; r < 8; ++r) { tA[r] = tp[r]; cA[r] = cp[r]; }
    }

    float acc = 0.f;
    for (int i = 0; i < count; i += 2) {
      const bool haveB = (i + 1 < count);
      if (haveB) {
        const float4* tp = reinterpret_cast<const float4*>(tbase + (size_t)spair[i + 1] * TROW);
        const float4* cp = reinterpret_cast<const float4*>(cbase + (size_t)sd2[i + 1] * 256);
#pragma unroll
        for (int r = 0; r < 8; ++r) { tB[r] = tp[r]; cB[r] = cp[r]; }
      }
      {
        float s = 0.f;
#pragma unroll
        for (int r = 0; r < 8; ++r)
          s += tA[r].x * cA[r].x + tA[r].y * cA[r].y + tA[r].z * cA[r].z + tA[r].w * cA[r].w;
        acc += s;
        if (!haveB || sbag[i + 1] != sbag[i]) {
          atomicAdd(out + (size_t)sbag[i] * 128 + tid, acc);
          acc = 0.f;
        }
      }
      if (haveB) {
        if (i + 2 < count) {
          const float4* tp = reinterpret_cast<const float4*>(tbase + (size_t)spair[i + 2] * TROW);
          const float4* cp = reinterpret_cast<const float4*>(cbase + (size_t)sd2[i + 2] * 256);
#pragma unroll
          for (int r = 0; r < 8; ++r) { tA[r] = tp[r]; cA[r] = cp[r]; }
        }
        float s = 0.f;
#pragma unroll
        for (int r = 0; r < 8; ++r)
          s += tB[r].x * cB[r].x + tB[r].y * cB[r].y + tB[r].z * cB[r].z + tB[r].w * cB[r].w;
        acc += s;
        if (i + 2 >= count || sbag[i + 2] != sbag[i + 1]) {
          atomicAdd(out + (size_t)sbag[i + 1] * 128 + tid, acc);
          acc = 0.f;
        }
      }
    }
  } else {
    // ---------------- cached part ----------------
    __shared__ int sci[CHC], sbg[CHC];
    const int cbid = bid - ntt_blocks;
    const int base = cbid * CHC;
    const int count = min(CHC, n - base);
    if (tid < count) {
      const int p = base + tid;
      sci[tid] = cached_indices[p];
      sbg[tid] = bag_search(cached_offsets, nbags, p);
    }
    __syncthreads();

    float acc = 0.f;
#pragma unroll 4
    for (int i = 0; i < count; ++i) {
      acc += cache_table[(size_t)sci[i] * 128 + tid];
      if (i + 1 >= count || sbg[i + 1] != sbg[i]) {
        atomicAdd(out + (size_t)sbg[i] * 128 + tid, acc);
        acc = 0.f;
      }
    }
  }
}

extern "C" void kernel_launch(void* const* d_in, const int* in_sizes, int n_in,
                              void* d_out, int out_size, void* d_ws, size_t ws_size,
                              hipStream_t stream) {
  const int* indices        = (const int*)d_in[0];
  const int* offsets        = (const int*)d_in[1];
  const int* cached_indices = (const int*)d_in[2];
  const int* cached_offsets = (const int*)d_in[3];
  const float* core0        = (const float*)d_in[4];
  const float* core1        = (const float*)d_in[5];
  const float* core2        = (const float*)d_in[6];
  const float* cache_table  = (const float*)d_in[7];
  float* out = (float*)d_out;

  const int n = in_sizes[0];             // 204800
  const int nbags = in_sizes[1] - 1;     // 4096

  float* t_table = (float*)d_ws;                                       // 5,120,000 B
  float* core2T  = (float*)((char*)d_ws + (size_t)PAIRS * TROW * 4);   // +51,200 B

  hipMemsetAsync(out, 0, (size_t)out_size * sizeof(float), stream);

  build_tables_kernel<<<PAIRS + 50, 256, 0, stream>>>(core0, core1, core2,
                                                      t_table, core2T);

  const int ntt = (n + CHT - 1) / CHT;   // 3200
  const int nc  = (n + CHC - 1) / CHC;   // 3200
  bag_main_kernel<<<ntt + nc, 128, 0, stream>>>(
      indices, offsets, cached_indices, cached_offsets, cache_table, t_table,
      core2T, out, n, nbags, ntt);
}

// Round 4
// 178.605 us; speedup vs baseline: 3.9947x; 3.9947x over previous
//
#include <hip/hip_runtime.h>
#include <hip/hip_bf16.h>

// TT embedding bag, three-phase:
//  1) build_tables: t_bf[pair][kk*32+s] (bf16, 2.56MB), c2T[d2][z*32+r] (fp32, 50KB)
//  2) emb_kernel:   emb[i][k] = dot32(t_bf[pair(i)][kk*32..], c2T[d2(i)][z*32..]) (bf16)
//  3) sum_kernel:   chunked segment-sum of emb rows + cache_table gather, atomic flush
// idx = pair*50 + d2 ; k = kk*8+z

#define PAIRS 2500
#define TROW 512
#define CHT 128
#define CHC 128

typedef unsigned int uint32_tt;
typedef unsigned short ushort_tt;

__device__ __forceinline__ float bflo(uint32_tt u) { return __uint_as_float(u << 16); }
__device__ __forceinline__ float bfhi(uint32_tt u) { return __uint_as_float(u & 0xffff0000u); }
__device__ __forceinline__ float bfu(ushort_tt u) { return __uint_as_float(((uint32_tt)u) << 16); }
__device__ __forceinline__ ushort_tt f2bf(float x) {
  __hip_bfloat16 h = __float2bfloat16(x);
  return *reinterpret_cast<ushort_tt*>(&h);
}

__global__ __launch_bounds__(256) void build_tables_kernel(
    const float* __restrict__ core0, const float* __restrict__ core1,
    const float* __restrict__ core2, ushort_tt* __restrict__ t_bf,
    float* __restrict__ c2T) {
  const int bid = blockIdx.x;
  const int tid = threadIdx.x;
  if (bid < PAIRS) {
    __shared__ float c0s[128];
    __shared__ float c1s[4096];
    const int d0 = bid / 50, d1 = bid - d0 * 50;
    const float4* src1 = reinterpret_cast<const float4*>(core1 + (size_t)d1 * 4096);
    float4* dst1 = reinterpret_cast<float4*>(c1s);
    for (int i = tid; i < 1024; i += 256) dst1[i] = src1[i];
    if (tid < 32) {
      reinterpret_cast<float4*>(c0s)[tid] =
          reinterpret_cast<const float4*>(core0 + (size_t)d0 * 128)[tid];
    }
    __syncthreads();
#pragma unroll
    for (int q = 0; q < 2; ++q) {
      const int o = tid + q * 256;
      const int kk = o >> 5, s = o & 31;
      const int x = kk >> 2, y = kk & 3;
      float acc = 0.f;
#pragma unroll
      for (int r = 0; r < 32; ++r)
        acc += c0s[x * 32 + r] * c1s[r * 128 + y * 32 + s];
      t_bf[(size_t)bid * TROW + o] = f2bf(acc);
    }
  } else {
    const int d2 = bid - PAIRS;
    if (tid < 256) {
      const int z = tid >> 5, r = tid & 31;
      c2T[(size_t)d2 * 256 + tid] = core2[(size_t)d2 * 256 + r * 8 + z];
    }
  }
}

#define TT_DOT_BODY(PAIRV, D2V, KKV, ZV, SOUT)                                        \
  {                                                                                    \
    const uint4* tp = reinterpret_cast<const uint4*>(t_bf + (size_t)(PAIRV)*TROW + (KKV)*32); \
    const float4* cp = reinterpret_cast<const float4*>(c2T + (size_t)(D2V)*256 + (ZV)*32);    \
    const uint4 t0 = tp[0], t1 = tp[1], t2 = tp[2], t3 = tp[3];                        \
    const float4 c0 = cp[0], c1 = cp[1], c2 = cp[2], c3 = cp[3];                       \
    const float4 c4 = cp[4], c5 = cp[5], c6 = cp[6], c7 = cp[7];                       \
    float s = 0.f;                                                                     \
    s += bflo(t0.x) * c0.x + bfhi(t0.x) * c0.y + bflo(t0.y) * c0.z + bfhi(t0.y) * c0.w; \
    s += bflo(t0.z) * c1.x + bfhi(t0.z) * c1.y + bflo(t0.w) * c1.z + bfhi(t0.w) * c1.w; \
    s += bflo(t1.x) * c2.x + bfhi(t1.x) * c2.y + bflo(t1.y) * c2.z + bfhi(t1.y) * c2.w; \
    s += bflo(t1.z) * c3.x + bfhi(t1.z) * c3.y + bflo(t1.w) * c3.z + bfhi(t1.w) * c3.w; \
    s += bflo(t2.x) * c4.x + bfhi(t2.x) * c4.y + bflo(t2.y) * c4.z + bfhi(t2.y) * c4.w; \
    s += bflo(t2.z) * c5.x + bfhi(t2.z) * c5.y + bflo(t2.w) * c5.z + bfhi(t2.w) * c5.w; \
    s += bflo(t3.x) * c6.x + bfhi(t3.x) * c6.y + bflo(t3.y) * c6.z + bfhi(t3.y) * c6.w; \
    s += bflo(t3.z) * c7.x + bfhi(t3.z) * c7.y + bflo(t3.w) * c7.z + bfhi(t3.w) * c7.w; \
    SOUT = s;                                                                          \
  }

__global__ __launch_bounds__(256, 4) void emb_kernel(
    const int* __restrict__ indices, const ushort_tt* __restrict__ t_bf,
    const float* __restrict__ c2T, ushort_tt* __restrict__ emb, int n) {
  const int tid = threadIdx.x;
  const int i = blockIdx.x * 2 + (tid >> 7);
  if (i >= n) return;
  const int k = tid & 127, kk = k >> 3, z = k & 7;
  const int idx = indices[i];
  const int pair = idx / 50;
  const int d2 = idx - pair * 50;
  float s;
  TT_DOT_BODY(pair, d2, kk, z, s);
  emb[(size_t)i * 128 + k] = f2bf(s);
}

__device__ __forceinline__ int bag_search(const int* __restrict__ offs,
                                          int nbags, int p) {
  int lo = 0, hi = nbags;
  while (hi - lo > 1) {
    int m = (lo + hi) >> 1;
    if (offs[m] <= p) lo = m; else hi = m;
  }
  return lo;
}

__global__ __launch_bounds__(128, 4) void sum_kernel(
    const ushort_tt* __restrict__ emb, const int* __restrict__ offsets,
    const int* __restrict__ cached_indices, const int* __restrict__ cached_offsets,
    const float* __restrict__ cache_table, float* __restrict__ out,
    int n, int nbags, int ntt_blocks) {
  const int tid = threadIdx.x;
  const int bid = blockIdx.x;

  if (bid < ntt_blocks) {
    // ------- TT part: streaming coalesced reads of emb rows -------
    __shared__ int sbag[CHT];
    const int base = bid * CHT;
    const int count = min(CHT, n - base);
    if (tid < count) sbag[tid] = bag_search(offsets, nbags, base + tid);
    __syncthreads();

    float acc = 0.f;
    float v0[8];
#pragma unroll
    for (int j = 0; j < 8; ++j)
      v0[j] = (j < count) ? bfu(emb[(size_t)(base + j) * 128 + tid]) : 0.f;

    for (int i0 = 0; i0 < count; i0 += 8) {
      float v1[8];
#pragma unroll
      for (int j = 0; j < 8; ++j)
        v1[j] = (i0 + 8 + j < count) ? bfu(emb[(size_t)(base + i0 + 8 + j) * 128 + tid]) : 0.f;
#pragma unroll
      for (int j = 0; j < 8; ++j) {
        const int i = i0 + j;
        if (i < count) {
          acc += v0[j];
          if (i + 1 == count || sbag[i + 1] != sbag[i]) {
            atomicAdd(out + (size_t)sbag[i] * 128 + tid, acc);
            acc = 0.f;
          }
        }
      }
#pragma unroll
      for (int j = 0; j < 8; ++j) v0[j] = v1[j];
    }
  } else {
    // ------- cached part: 8-deep pipelined row gather -------
    __shared__ int sci[CHC], sbg[CHC];
    const int cbid = bid - ntt_blocks;
    const int base = cbid * CHC;
    const int count = min(CHC, n - base);
    if (tid < count) {
      const int p = base + tid;
      sci[tid] = cached_indices[p];
      sbg[tid] = bag_search(cached_offsets, nbags, p);
    }
    __syncthreads();

    float acc = 0.f;
    float v0[8];
#pragma unroll
    for (int j = 0; j < 8; ++j)
      v0[j] = (j < count) ? cache_table[(size_t)sci[j] * 128 + tid] : 0.f;

    for (int i0 = 0; i0 < count; i0 += 8) {
      float v1[8];
#pragma unroll
      for (int j = 0; j < 8; ++j)
        v1[j] = (i0 + 8 + j < count) ? cache_table[(size_t)sci[i0 + 8 + j] * 128 + tid] : 0.f;
#pragma unroll
      for (int j = 0; j < 8; ++j) {
        const int i = i0 + j;
        if (i < count) {
          acc += v0[j];
          if (i + 1 == count || sbg[i + 1] != sbg[i]) {
            atomicAdd(out + (size_t)sbg[i] * 128 + tid, acc);
            acc = 0.f;
          }
        }
      }
#pragma unroll
      for (int j = 0; j < 8; ++j) v0[j] = v1[j];
    }
  }
}

// Fallback (workspace too small to materialize emb): fused TT segment-sum.
__global__ __launch_bounds__(128) void fused_tt_kernel(
    const int* __restrict__ indices, const int* __restrict__ offsets,
    const ushort_tt* __restrict__ t_bf, const float* __restrict__ c2T,
    float* __restrict__ out, int n, int nbags) {
  __shared__ int spair[32], sd2[32], sbag[32];
  const int tid = threadIdx.x;
  const int base = blockIdx.x * 32;
  const int count = min(32, n - base);
  if (tid < count) {
    const int p = base + tid;
    const int idx = indices[p];
    const int pr = idx / 50;
    spair[tid] = pr;
    sd2[tid] = idx - pr * 50;
    sbag[tid] = bag_search(offsets, nbags, p);
  }
  __syncthreads();
  const int kk = tid >> 3, z = tid & 7;
  float acc = 0.f;
  for (int i = 0; i < count; ++i) {
    float s;
    TT_DOT_BODY(spair[i], sd2[i], kk, z, s);
    acc += s;
    if (i + 1 == count || sbag[i + 1] != sbag[i]) {
      atomicAdd(out + (size_t)sbag[i] * 128 + tid, acc);
      acc = 0.f;
    }
  }
}

extern "C" void kernel_launch(void* const* d_in, const int* in_sizes, int n_in,
                              void* d_out, int out_size, void* d_ws, size_t ws_size,
                              hipStream_t stream) {
  const int* indices        = (const int*)d_in[0];
  const int* offsets        = (const int*)d_in[1];
  const int* cached_indices = (const int*)d_in[2];
  const int* cached_offsets = (const int*)d_in[3];
  const float* core0        = (const float*)d_in[4];
  const float* core1        = (const float*)d_in[5];
  const float* core2        = (const float*)d_in[6];
  const float* cache_table  = (const float*)d_in[7];
  float* out = (float*)d_out;

  const int n = in_sizes[0];             // 204800
  const int nbags = in_sizes[1] - 1;     // 4096

  // workspace layout
  const size_t t_bf_bytes = (size_t)PAIRS * TROW * 2;      // 2,560,000
  const size_t c2T_bytes  = (size_t)50 * 256 * 4;          // 51,200
  ushort_tt* t_bf = (ushort_tt*)d_ws;
  float* c2T = (float*)((char*)d_ws + t_bf_bytes);
  ushort_tt* emb = (ushort_tt*)((char*)d_ws + t_bf_bytes + c2T_bytes);
  const size_t need = t_bf_bytes + c2T_bytes + (size_t)n * 128 * 2;

  hipMemsetAsync(out, 0, (size_t)out_size * sizeof(float), stream);

  build_tables_kernel<<<PAIRS + 50, 256, 0, stream>>>(core0, core1, core2, t_bf, c2T);

  const int nc = (n + CHC - 1) / CHC;
  if (ws_size >= need) {
    emb_kernel<<<(n + 1) / 2, 256, 0, stream>>>(indices, t_bf, c2T, emb, n);
    const int ntt = (n + CHT - 1) / CHT;
    sum_kernel<<<ntt + nc, 128, 0, stream>>>(
        emb, offsets, cached_indices, cached_offsets, cache_table, out,
        n, nbags, ntt);
  } else {
    fused_tt_kernel<<<(n + 31) / 32, 128, 0, stream>>>(indices, offsets, t_bf,
                                                       c2T, out, n, nbags);
    sum_kernel<<<nc, 128, 0, stream>>>(
        emb, offsets, cached_indices, cached_offsets, cache_table, out,
        n, nbags, 0);
  }
}